// Round 4
// baseline (20218.695 us; speedup 1.0000x reference)
//
#include <hip/hip_runtime.h>
#include <hip/hip_bf16.h>
#include <stdint.h>

// ---------------- direct 3x3 conv, pad=1, stride S, NCHW, fp32 ----------------
template<int CIN, int COUT, int HIN, int WIN, int S>
__global__ void conv3x3_kernel(const float* __restrict__ x, const float* __restrict__ w,
                               const float* __restrict__ bias, float* __restrict__ y,
                               int total, int relu)
{
    constexpr int HOUT = (HIN - 1) / S + 1;
    constexpr int WOUT = (WIN - 1) / S + 1;
    int idx = blockIdx.x * blockDim.x + threadIdx.x;
    if (idx >= total) return;
    int wo = idx % WOUT;
    int t  = idx / WOUT;
    int ho = t % HOUT; t /= HOUT;
    int co = t % COUT;
    int n  = t / COUT;

    float acc = bias[co];
    const float* xn = x + (size_t)n * CIN * HIN * WIN;
    const float* wc = w + (size_t)co * CIN * 9;
    for (int ci = 0; ci < CIN; ++ci) {
        const float* xc = xn + ci * HIN * WIN;
        const float* wk = wc + ci * 9;
        #pragma unroll
        for (int kh = 0; kh < 3; ++kh) {
            int hi = ho * S - 1 + kh;
            if ((unsigned)hi >= (unsigned)HIN) continue;
            #pragma unroll
            for (int kw = 0; kw < 3; ++kw) {
                int wi = wo * S - 1 + kw;
                if ((unsigned)wi >= (unsigned)WIN) continue;
                acc += xc[hi * WIN + wi] * wk[kh * 3 + kw];
            }
        }
    }
    if (relu) acc = fmaxf(acc, 0.f);
    y[idx] = acc;
}

// ---------------- transpose conv k=3, pad=1, out_pad=S-1 (gather form), fp32 ----------------
// weight layout (CIN, COUT, 3, 3)  [torch ConvTranspose2d]
template<int CIN, int COUT, int HIN, int WIN, int S>
__global__ void convt3x3_kernel(const float* __restrict__ x, const float* __restrict__ w,
                                const float* __restrict__ bias, float* __restrict__ y,
                                int total)
{
    int idx = blockIdx.x * blockDim.x + threadIdx.x;
    if (idx >= total) return;
    constexpr int HOUT = HIN * S;
    constexpr int WOUT = WIN * S;
    int wo = idx % WOUT;
    int t  = idx / WOUT;
    int ho = t % HOUT; t /= HOUT;
    int co = t % COUT;
    int n  = t / COUT;

    float acc = bias[co];
    const float* xn = x + (size_t)n * CIN * HIN * WIN;
    #pragma unroll
    for (int kh = 0; kh < 3; ++kh) {
        int th = ho + 1 - kh;
        if (S == 2 && (th & 1)) continue;
        int hi = th / S;
        if ((unsigned)hi >= (unsigned)HIN) continue;
        #pragma unroll
        for (int kw = 0; kw < 3; ++kw) {
            int tw = wo + 1 - kw;
            if (S == 2 && (tw & 1)) continue;
            int wi = tw / S;
            if ((unsigned)wi >= (unsigned)WIN) continue;
            const float* xp = xn + hi * WIN + wi;
            const float* wp = w + (size_t)co * 9 + kh * 3 + kw;
            float a = 0.f;
            for (int ci = 0; ci < CIN; ++ci)
                a += xp[(size_t)ci * HIN * WIN] * wp[(size_t)ci * COUT * 9];
            acc += a;
        }
    }
    acc = fmaxf(acc, 0.f);  // all transpose convs here have relu
    y[idx] = acc;
}

// ---------------- final 1x1 conv 16->3, bias, no relu ----------------
__global__ void conv1x1_16_3(const float* __restrict__ x, const float* __restrict__ w,
                             const float* __restrict__ bias, float* __restrict__ y, int total)
{
    int idx = blockIdx.x * blockDim.x + threadIdx.x;
    if (idx >= total) return;
    int p  = idx % 1024;
    int t  = idx / 1024;
    int co = t % 3;
    int n  = t / 3;
    float acc = bias[co];
    const float* xp = x + (size_t)n * 16 * 1024 + p;
    #pragma unroll
    for (int ci = 0; ci < 16; ++ci)
        acc += xp[ci * 1024] * w[co * 16 + ci];
    y[idx] = acc;
}

// ---------------- embedding: sigmoid(h3(chunk,4096) @ kw^T(4096,110) + kb) ----------------
__global__ void emb_kernel(const float* __restrict__ h3, const float* __restrict__ kw,
                           const float* __restrict__ kb, float* __restrict__ emb)
{
    __shared__ float row[4096];
    int n = blockIdx.x;
    const float* src = h3 + (size_t)n * 4096;
    for (int k = threadIdx.x; k < 4096; k += blockDim.x) row[k] = src[k];
    __syncthreads();
    int e = threadIdx.x;
    if (e < 110) {
        float acc = kb[e];
        const float* kwr = kw + (size_t)e * 4096;
        for (int k = 0; k < 4096; ++k) acc += row[k] * kwr[k];
        emb[(size_t)n * 110 + e] = 1.f / (1.f + expf(-acc));
    }
}

// ---------------- KDE: emb(64,32,110) -> fd(64, 110*11) ----------------
__global__ void kde_kernel(const float* __restrict__ emb, float* __restrict__ fd)
{
    int idx = blockIdx.x * blockDim.x + threadIdx.x;
    if (idx >= 64 * 110) return;
    int f = idx % 110;
    int b = idx / 110;
    float dens[11];
    #pragma unroll
    for (int j = 0; j < 11; ++j) dens[j] = 0.f;
    const float* ep = emb + (size_t)b * 32 * 110 + f;
    for (int n = 0; n < 32; ++n) {
        float e = ep[n * 110];
        #pragma unroll
        for (int j = 0; j < 11; ++j) {
            float d = 0.1f * j - e;
            dens[j] += expf(-50.f * d * d);
        }
    }
    float s = 0.f;
    #pragma unroll
    for (int j = 0; j < 11; ++j) s += dens[j];
    float inv = 1.f / s;
    float* op = fd + (size_t)b * 1210 + f * 11;
    #pragma unroll
    for (int j = 0; j < 11; ++j) op[j] = dens[j] * inv;
}

// ---------------- dense layers (fp32) ----------------
template<int K, int OUT>
__global__ void dense_kernel(const float* __restrict__ in, const float* __restrict__ w,
                             const float* __restrict__ b, float* __restrict__ out,
                             int rows, int relu)
{
    int idx = blockIdx.x * blockDim.x + threadIdx.x;
    if (idx >= rows * OUT) return;
    int o = idx % OUT;
    int r = idx / OUT;
    float acc = b[o];
    const float* ir = in + (size_t)r * K;
    const float* wr = w  + (size_t)o * K;
    for (int k = 0; k < K; ++k) acc += ir[k] * wr[k];
    if (relu) acc = fmaxf(acc, 0.f);
    out[idx] = acc;
}

extern "C" void kernel_launch(void* const* d_in, const int* in_sizes, int n_in,
                              void* d_out, int out_size, void* d_ws, size_t ws_size,
                              hipStream_t stream)
{
    const float* x    = (const float*)d_in[0];
    const float* ew1  = (const float*)d_in[1];
    const float* eb1  = (const float*)d_in[2];
    const float* ew2  = (const float*)d_in[3];
    const float* eb2  = (const float*)d_in[4];
    const float* ew3  = (const float*)d_in[5];
    const float* eb3  = (const float*)d_in[6];
    const float* kw   = (const float*)d_in[7];
    const float* kb   = (const float*)d_in[8];
    const float* dw1  = (const float*)d_in[9];
    const float* db1  = (const float*)d_in[10];
    const float* dw2  = (const float*)d_in[11];
    const float* db2  = (const float*)d_in[12];
    const float* dw3  = (const float*)d_in[13];
    const float* db3  = (const float*)d_in[14];
    const float* dw4  = (const float*)d_in[15];
    const float* db4  = (const float*)d_in[16];
    const float* f1w  = (const float*)d_in[17];
    const float* f1b  = (const float*)d_in[18];
    const float* f2w  = (const float*)d_in[19];
    const float* f2b_ = (const float*)d_in[20];
    const float* f3w  = (const float*)d_in[21];
    const float* f3b  = (const float*)d_in[22];

    // ---------- workspace layout, sized to the ACTUAL ws_size ----------
    char* ws = (char*)d_ws;
    float* emb = (float*)(ws + 0);              //   901,120 B (2048*110 f32)
    float* fd  = (float*)(ws + 901120);         //   309,760 B (64*1210)
    float* m1  = (float*)(ws + 1210880);        //   131,072 B (64*512)
    float* m2  = (float*)(ws + 1341952);        //    65,536 B (64*256)
    const size_t FIXED = 1407488;

    // per-image fp32 buffers (d1 overlays h1; both 64 KB):
    //   h1/d1 64K | h2 32K | h3 16K | d2 128K | d3 64K  = 304 KB/image
    const size_t PER_IMG = 311296;
    int CHUNK = 256;
    while (CHUNK > 8 && FIXED + (size_t)CHUNK * PER_IMG > ws_size) CHUNK >>= 1;
    const int NCHUNK = 2048 / CHUNK;

    char* p   = ws + FIXED;
    float* h1 = (float*)(p);                                   // CHUNK*16*1024
    float* h2 = (float*)(p + (size_t)CHUNK * 65536);           // CHUNK*32*256
    float* h3 = (float*)(p + (size_t)CHUNK * 98304);           // CHUNK*64*64
    float* d2 = (float*)(p + (size_t)CHUNK * 114688);          // CHUNK*32*1024
    float* d3 = (float*)(p + (size_t)CHUNK * 245760);          // CHUNK*16*1024
    float* d1 = h1;                                            // reuse (h1 dead after conv2)

    float* logits = (float*)d_out;              // 64*4
    float* dec    = (float*)d_out + 256;        // 2048*3*32*32

    for (int c = 0; c < NCHUNK; ++c) {
        const float* xc   = x   + (size_t)c * CHUNK * 3 * 1024;
        float*       decc = dec + (size_t)c * CHUNK * 3 * 1024;
        float*       embc = emb + (size_t)c * CHUNK * 110;

        // encoder
        { int total = CHUNK*16*1024;
          conv3x3_kernel<3,16,32,32,1><<<(total+255)/256,256,0,stream>>>(xc, ew1, eb1, h1, total, 1); }
        { int total = CHUNK*32*256;
          conv3x3_kernel<16,32,32,32,2><<<(total+255)/256,256,0,stream>>>(h1, ew2, eb2, h2, total, 1); }
        { int total = CHUNK*64*64;
          conv3x3_kernel<32,64,16,16,2><<<(total+255)/256,256,0,stream>>>(h2, ew3, eb3, h3, total, 1); }

        // embedding
        emb_kernel<<<CHUNK,128,0,stream>>>(h3, kw, kb, embc);

        // decoder
        { int total = CHUNK*64*256;
          convt3x3_kernel<64,64,8,8,2><<<(total+255)/256,256,0,stream>>>(h3, dw1, db1, d1, total); }
        { int total = CHUNK*32*1024;
          convt3x3_kernel<64,32,16,16,2><<<(total+255)/256,256,0,stream>>>(d1, dw2, db2, d2, total); }
        { int total = CHUNK*16*1024;
          convt3x3_kernel<32,16,32,32,1><<<(total+255)/256,256,0,stream>>>(d2, dw3, db3, d3, total); }
        { int total = CHUNK*3*1024;
          conv1x1_16_3<<<(total+255)/256,256,0,stream>>>(d3, dw4, db4, decc, total); }
    }

    // classifier
    kde_kernel<<<(64*110+255)/256,256,0,stream>>>(emb, fd);
    dense_kernel<1210,512><<<(64*512+255)/256,256,0,stream>>>(fd, f1w, f1b, m1, 64, 1);
    dense_kernel<512,256><<<(64*256+255)/256,256,0,stream>>>(m1, f2w, f2b_, m2, 64, 1);
    dense_kernel<256,4><<<1,256,0,stream>>>(m2, f3w, f3b, logits, 64, 0);
}

// Round 5
// 13293.394 us; speedup vs baseline: 1.5210x; 1.5210x over previous
//
#include <hip/hip_runtime.h>
#include <hip/hip_bf16.h>
#include <stdint.h>

// ============ register-blocked direct 3x3 conv, pad=1, stride S ============
// Each thread: HBLK x WBLK output tile for one (n, co). Weights loaded once
// per ci (9 regs); input rows streamed one at a time (NC regs live).
template<int CIN, int COUT, int HIN, int WIN, int S, int HBLK, int WBLK>
__global__ void conv_blk(const float* __restrict__ x, const float* __restrict__ w,
                         const float* __restrict__ bias, float* __restrict__ y,
                         int nimg, int relu)
{
    constexpr int HOUT = (HIN - 1) / S + 1;
    constexpr int WOUT = (WIN - 1) / S + 1;
    constexpr int HG = HOUT / HBLK, WG = WOUT / WBLK;
    constexpr int NR = (HBLK - 1) * S + 3;      // input rows touched
    constexpr int NC = (WBLK - 1) * S + 3;      // input cols touched
    int idx = blockIdx.x * blockDim.x + threadIdx.x;
    int total = nimg * COUT * HG * WG;
    if (idx >= total) return;
    int wg = idx % WG; int t = idx / WG;
    int hg = t % HG;  t /= HG;
    int co = t % COUT; int n = t / COUT;
    int ho0 = hg * HBLK, wo0 = wg * WBLK;
    const int hb = ho0 * S - 1, wb = wo0 * S - 1;

    float acc[HBLK][WBLK];
    float bv = bias[co];
    #pragma unroll
    for (int a = 0; a < HBLK; ++a)
        #pragma unroll
        for (int b = 0; b < WBLK; ++b) acc[a][b] = bv;

    const float* xn = x + (size_t)n * CIN * HIN * WIN;
    const float* wc = w + (size_t)co * CIN * 9;
    for (int ci = 0; ci < CIN; ++ci) {
        const float* xc = xn + ci * HIN * WIN;
        const float* wp = wc + ci * 9;
        float wr[9];
        #pragma unroll
        for (int q = 0; q < 9; ++q) wr[q] = wp[q];
        #pragma unroll
        for (int r = 0; r < NR; ++r) {          // stream input rows
            int hi = hb + r;
            float row[NC];
            #pragma unroll
            for (int c = 0; c < NC; ++c) {
                int wi = wb + c;
                row[c] = ((unsigned)hi < (unsigned)HIN && (unsigned)wi < (unsigned)WIN)
                         ? xc[hi * WIN + wi] : 0.f;
            }
            #pragma unroll
            for (int dh = 0; dh < HBLK; ++dh)
                #pragma unroll
                for (int kh = 0; kh < 3; ++kh) {
                    if (dh * S + kh != r) continue;          // compile-time match
                    #pragma unroll
                    for (int i = 0; i < WBLK; ++i)
                        #pragma unroll
                        for (int kw = 0; kw < 3; ++kw)
                            acc[dh][i] += row[i * S + kw] * wr[kh * 3 + kw];
                }
        }
    }
    #pragma unroll
    for (int dh = 0; dh < HBLK; ++dh)
        #pragma unroll
        for (int i = 0; i < WBLK; ++i) {
            float v = acc[dh][i];
            if (relu) v = fmaxf(v, 0.f);
            y[(((size_t)n * COUT + co) * HOUT + ho0 + dh) * WOUT + wo0 + i] = v;
        }
}

// ============ register-blocked transpose conv k=3, pad=1, out_pad=S-1 ======
// weight layout (CIN, COUT, 3, 3). Gather form; parity resolved compile-time.
template<int CIN, int COUT, int HIN, int WIN, int S, int HBLK, int WBLK>
__global__ void convt_blk(const float* __restrict__ x, const float* __restrict__ w,
                          const float* __restrict__ bias, float* __restrict__ y,
                          int nimg)
{
    constexpr int HOUT = HIN * S, WOUT = WIN * S;
    constexpr int HG = HOUT / HBLK, WG = WOUT / WBLK;
    constexpr int NR = (S == 2) ? (HBLK / 2 + 1) : (HBLK + 2);
    constexpr int NC = (S == 2) ? (WBLK / 2 + 1) : (WBLK + 2);
    int idx = blockIdx.x * blockDim.x + threadIdx.x;
    int total = nimg * COUT * HG * WG;
    if (idx >= total) return;
    int wg = idx % WG; int t = idx / WG;
    int hg = t % HG;  t /= HG;
    int co = t % COUT; int n = t / COUT;
    int ho0 = hg * HBLK, wo0 = wg * WBLK;      // ho0, wo0 even when S==2 (HBLK=2, WBLK=8)
    const int hb = (S == 2) ? ho0 / 2 : ho0 - 1;
    const int wb = (S == 2) ? wo0 / 2 : wo0 - 1;

    float acc[HBLK][WBLK];
    float bv = bias[co];
    #pragma unroll
    for (int a = 0; a < HBLK; ++a)
        #pragma unroll
        for (int b = 0; b < WBLK; ++b) acc[a][b] = bv;

    const float* xn = x + (size_t)n * CIN * HIN * WIN;
    for (int ci = 0; ci < CIN; ++ci) {
        const float* xc = xn + ci * HIN * WIN;
        const float* wp = w + ((size_t)ci * COUT + co) * 9;
        float wr[9];
        #pragma unroll
        for (int q = 0; q < 9; ++q) wr[q] = wp[q];
        #pragma unroll
        for (int r = 0; r < NR; ++r) {          // stream input rows
            int hi = hb + r;
            float row[NC];
            #pragma unroll
            for (int c = 0; c < NC; ++c) {
                int wi = wb + c;
                row[c] = ((unsigned)hi < (unsigned)HIN && (unsigned)wi < (unsigned)WIN)
                         ? xc[hi * WIN + wi] : 0.f;
            }
            #pragma unroll
            for (int dh = 0; dh < HBLK; ++dh)
                #pragma unroll
                for (int kh = 0; kh < 3; ++kh) {
                    if (S == 2 && ((dh + 1 - kh) & 1)) continue;       // parity skip
                    constexpr int dummy = 0; (void)dummy;
                    int rr = (S == 2) ? (dh + 1 - kh) / 2 : (dh + 2 - kh);
                    if (rr != r) continue;                             // compile-time match
                    #pragma unroll
                    for (int i = 0; i < WBLK; ++i)
                        #pragma unroll
                        for (int kw = 0; kw < 3; ++kw) {
                            if (S == 2 && ((i + 1 - kw) & 1)) continue;
                            int c = (S == 2) ? (i + 1 - kw) / 2 : (i + 2 - kw);
                            acc[dh][i] += row[c] * wr[kh * 3 + kw];
                        }
                }
        }
    }
    #pragma unroll
    for (int dh = 0; dh < HBLK; ++dh)
        #pragma unroll
        for (int i = 0; i < WBLK; ++i)
            y[(((size_t)n * COUT + co) * HOUT + ho0 + dh) * WOUT + wo0 + i]
                = fmaxf(acc[dh][i], 0.f);       // all transpose convs have relu
}

// ---------------- final 1x1 conv 16->3, bias, no relu ----------------
__global__ void conv1x1_16_3(const float* __restrict__ x, const float* __restrict__ w,
                             const float* __restrict__ bias, float* __restrict__ y, int total)
{
    int idx = blockIdx.x * blockDim.x + threadIdx.x;
    if (idx >= total) return;
    int p  = idx % 1024;
    int t  = idx / 1024;
    int co = t % 3;
    int n  = t / 3;
    float acc = bias[co];
    const float* xp = x + (size_t)n * 16 * 1024 + p;
    #pragma unroll
    for (int ci = 0; ci < 16; ++ci)
        acc += xp[ci * 1024] * w[co * 16 + ci];
    y[idx] = acc;
}

// ---------------- embedding: sigmoid(h3(n,4096) @ kw^T + kb), float4 ----------------
__global__ void emb_kernel(const float* __restrict__ h3, const float* __restrict__ kw,
                           const float* __restrict__ kb, float* __restrict__ emb)
{
    __shared__ float4 row[1024];
    int n = blockIdx.x;
    const float4* src = (const float4*)(h3 + (size_t)n * 4096);
    for (int k = threadIdx.x; k < 1024; k += blockDim.x) row[k] = src[k];
    __syncthreads();
    int e = threadIdx.x;
    if (e < 110) {
        const float4* kwr = (const float4*)(kw + (size_t)e * 4096);
        float s0 = 0.f, s1 = 0.f, s2 = 0.f, s3 = 0.f;
        for (int k = 0; k < 1024; k += 2) {
            float4 r0 = row[k],     w0 = kwr[k];
            float4 r1 = row[k + 1], w1 = kwr[k + 1];
            s0 += r0.x * w0.x + r1.x * w1.x;
            s1 += r0.y * w0.y + r1.y * w1.y;
            s2 += r0.z * w0.z + r1.z * w1.z;
            s3 += r0.w * w0.w + r1.w * w1.w;
        }
        float acc = kb[e] + ((s0 + s1) + (s2 + s3));
        emb[(size_t)n * 110 + e] = 1.f / (1.f + expf(-acc));
    }
}

// ---------------- KDE: emb(64,32,110) -> fd(64, 110*11) ----------------
__global__ void kde_kernel(const float* __restrict__ emb, float* __restrict__ fd)
{
    int idx = blockIdx.x * blockDim.x + threadIdx.x;
    if (idx >= 64 * 110) return;
    int f = idx % 110;
    int b = idx / 110;
    float dens[11];
    #pragma unroll
    for (int j = 0; j < 11; ++j) dens[j] = 0.f;
    const float* ep = emb + (size_t)b * 32 * 110 + f;
    for (int n = 0; n < 32; ++n) {
        float e = ep[n * 110];
        #pragma unroll
        for (int j = 0; j < 11; ++j) {
            float d = 0.1f * j - e;
            dens[j] += expf(-50.f * d * d);
        }
    }
    float s = 0.f;
    #pragma unroll
    for (int j = 0; j < 11; ++j) s += dens[j];
    float inv = 1.f / s;
    float* op = fd + (size_t)b * 1210 + f * 11;
    #pragma unroll
    for (int j = 0; j < 11; ++j) op[j] = dens[j] * inv;
}

// ---------------- dense layers (fp32) ----------------
template<int K, int OUT>
__global__ void dense_kernel(const float* __restrict__ in, const float* __restrict__ w,
                             const float* __restrict__ b, float* __restrict__ out,
                             int rows, int relu)
{
    int idx = blockIdx.x * blockDim.x + threadIdx.x;
    if (idx >= rows * OUT) return;
    int o = idx % OUT;
    int r = idx / OUT;
    float acc = b[o];
    const float* ir = in + (size_t)r * K;
    const float* wr = w  + (size_t)o * K;
    for (int k = 0; k < K; ++k) acc += ir[k] * wr[k];
    if (relu) acc = fmaxf(acc, 0.f);
    out[idx] = acc;
}

extern "C" void kernel_launch(void* const* d_in, const int* in_sizes, int n_in,
                              void* d_out, int out_size, void* d_ws, size_t ws_size,
                              hipStream_t stream)
{
    const float* x    = (const float*)d_in[0];
    const float* ew1  = (const float*)d_in[1];
    const float* eb1  = (const float*)d_in[2];
    const float* ew2  = (const float*)d_in[3];
    const float* eb2  = (const float*)d_in[4];
    const float* ew3  = (const float*)d_in[5];
    const float* eb3  = (const float*)d_in[6];
    const float* kw   = (const float*)d_in[7];
    const float* kb   = (const float*)d_in[8];
    const float* dw1  = (const float*)d_in[9];
    const float* db1  = (const float*)d_in[10];
    const float* dw2  = (const float*)d_in[11];
    const float* db2  = (const float*)d_in[12];
    const float* dw3  = (const float*)d_in[13];
    const float* db3  = (const float*)d_in[14];
    const float* dw4  = (const float*)d_in[15];
    const float* db4  = (const float*)d_in[16];
    const float* f1w  = (const float*)d_in[17];
    const float* f1b  = (const float*)d_in[18];
    const float* f2w  = (const float*)d_in[19];
    const float* f2b_ = (const float*)d_in[20];
    const float* f3w  = (const float*)d_in[21];
    const float* f3b  = (const float*)d_in[22];

    // ---------- workspace layout, sized to the ACTUAL ws_size ----------
    char* ws = (char*)d_ws;
    float* emb = (float*)(ws + 0);              //   901,120 B (2048*110 f32)
    float* fd  = (float*)(ws + 901120);         //   309,760 B
    float* m1  = (float*)(ws + 1210880);        //   131,072 B
    float* m2  = (float*)(ws + 1341952);        //    65,536 B
    const size_t FIXED = 1407488;

    const size_t PER_IMG = 311296;              // h1/d1 64K | h2 32K | h3 16K | d2 128K | d3 64K
    int CHUNK = 256;
    while (CHUNK > 8 && FIXED + (size_t)CHUNK * PER_IMG > ws_size) CHUNK >>= 1;
    const int NCHUNK = 2048 / CHUNK;

    char* p   = ws + FIXED;
    float* h1 = (float*)(p);
    float* h2 = (float*)(p + (size_t)CHUNK * 65536);
    float* h3 = (float*)(p + (size_t)CHUNK * 98304);
    float* d2 = (float*)(p + (size_t)CHUNK * 114688);
    float* d3 = (float*)(p + (size_t)CHUNK * 245760);
    float* d1 = h1;                              // reuse (h1 dead after conv2)

    float* logits = (float*)d_out;               // 64*4
    float* dec    = (float*)d_out + 256;         // 2048*3*32*32

    for (int c = 0; c < NCHUNK; ++c) {
        const float* xc   = x   + (size_t)c * CHUNK * 3 * 1024;
        float*       decc = dec + (size_t)c * CHUNK * 3 * 1024;
        float*       embc = emb + (size_t)c * CHUNK * 110;

        // encoder: conv<CIN,COUT,HIN,WIN,S,HBLK,WBLK>
        { int th = CHUNK * 16 * (32/2) * (32/8);     // 2x8 tiles
          conv_blk<3,16,32,32,1,2,8><<<(th+255)/256,256,0,stream>>>(xc, ew1, eb1, h1, CHUNK, 1); }
        { int th = CHUNK * 32 * (16/2) * (16/8);
          conv_blk<16,32,32,32,2,2,8><<<(th+255)/256,256,0,stream>>>(h1, ew2, eb2, h2, CHUNK, 1); }
        { int th = CHUNK * 64 * (8/2) * (8/8);
          conv_blk<32,64,16,16,2,2,8><<<(th+255)/256,256,0,stream>>>(h2, ew3, eb3, h3, CHUNK, 1); }

        // embedding
        emb_kernel<<<CHUNK,128,0,stream>>>(h3, kw, kb, embc);

        // decoder: convt<CIN,COUT,HIN,WIN,S,HBLK,WBLK>
        { int th = CHUNK * 64 * (16/2) * (16/8);
          convt_blk<64,64,8,8,2,2,8><<<(th+255)/256,256,0,stream>>>(h3, dw1, db1, d1, CHUNK); }
        { int th = CHUNK * 32 * (32/2) * (32/8);
          convt_blk<64,32,16,16,2,2,8><<<(th+255)/256,256,0,stream>>>(d1, dw2, db2, d2, CHUNK); }
        { int th = CHUNK * 16 * (32/2) * (32/8);
          convt_blk<32,16,32,32,1,2,8><<<(th+255)/256,256,0,stream>>>(d2, dw3, db3, d3, CHUNK); }
        { int total = CHUNK * 3 * 1024;
          conv1x1_16_3<<<(total+255)/256,256,0,stream>>>(d3, dw4, db4, decc, total); }
    }

    // classifier
    kde_kernel<<<(64*110+255)/256,256,0,stream>>>(emb, fd);
    dense_kernel<1210,512><<<(64*512+255)/256,256,0,stream>>>(fd, f1w, f1b, m1, 64, 1);
    dense_kernel<512,256><<<(64*256+255)/256,256,0,stream>>>(m1, f2w, f2b_, m2, 64, 1);
    dense_kernel<256,4><<<1,256,0,stream>>>(m2, f3w, f3b, logits, 64, 0);
}

// Round 6
// 3087.211 us; speedup vs baseline: 6.5492x; 4.3060x over previous
//
#include <hip/hip_runtime.h>
#include <hip/hip_bf16.h>
#include <stdint.h>

struct Taps  { int n; int oh[9]; int ow[9]; int ti[9]; };
struct Taps4 { Taps t[4]; };

// ===================== unified implicit-GEMM conv =====================
// y[n, ho, wo, co] (NHWC, or fused-NCHW-out) = relu( b[co] +
//   sum_{t,ci} x[n, hq*A+oh_t, wq*A+ow_t, ci] * wt[ti_t][ci][co] )
// ho = hq*OST + pa (class pa,pb from blockIdx.y when OST==2).
// Block: 256 threads; M=MH*MW positions x N=COUT cols; 4x4 per thread.
template<int CIN, int COUT, int HIN, int WIN, int HOUT, int WOUT,
         int A, int OST, int MH, int MW, int KC, bool IN_NCHW, bool FUSE>
__global__ __launch_bounds__(256)
void conv_gemm(const float* __restrict__ x, const float* __restrict__ wt,
               const float* __restrict__ bias, float* __restrict__ y,
               Taps4 ts, const float* __restrict__ w4, const float* __restrict__ b4)
{
    constexpr int M   = MH * MW;
    constexpr int N   = COUT;
    constexpr int NT4 = N / 4;
    constexpr int HQ  = HOUT / OST, WQ = WOUT / OST;
    constexpr int TH  = HQ / MH,   TW = WQ / MW;
    constexpr int XSTR = M + 4;
    constexpr int XSZ  = FUSE ? (KC * XSTR > M * 17 ? KC * XSTR : M * 17) : KC * XSTR;
    static_assert(M * N == 4096, "block tile must be 4096");

    __shared__ float Xs[XSZ];
    __shared__ float Ws[KC * N];

    const int tid = threadIdx.x;
    const int mt = tid / NT4, nt = tid % NT4;

    int bx = blockIdx.x;
    const int tw = bx % TW; bx /= TW;
    const int th = bx % TH;
    const int n  = bx / TH;
    const int cls = (OST == 2) ? (int)blockIdx.y : 0;
    const int pa  = (OST == 2) ? (cls >> 1) : 0;
    const int pb  = (OST == 2) ? (cls & 1) : 0;
    const int hq0 = th * MH, wq0 = tw * MW;

    float bv[4];
    #pragma unroll
    for (int j = 0; j < 4; ++j) bv[j] = bias[nt * 4 + j];

    float acc[4][4];
    #pragma unroll
    for (int i = 0; i < 4; ++i)
        #pragma unroll
        for (int j = 0; j < 4; ++j) acc[i][j] = 0.f;

    const int ntaps = ts.t[cls].n;
    for (int t = 0; t < ntaps; ++t) {
        const int oh = ts.t[cls].oh[t];
        const int ow = ts.t[cls].ow[t];
        const int ti = ts.t[cls].ti[t];
        const float* wtp = wt + (size_t)(ti * CIN) * N;
        for (int c0 = 0; c0 < CIN; c0 += KC) {
            __syncthreads();
            // ---- stage W chunk: KC x N, contiguous ----
            for (int e = tid; e < KC * N; e += 256)
                Ws[e] = wtp[(size_t)c0 * N + e];
            // ---- stage X chunk: KC x M, zero-padded at borders ----
            for (int e = tid; e < M * KC; e += 256) {
                int k, m;
                if (IN_NCHW) { k = e / M;  m = e % M; }
                else         { k = e % KC; m = e / KC; }
                const int hq = hq0 + m / MW;
                const int wq = wq0 + m % MW;
                const int hi = hq * A + oh;
                const int wi = wq * A + ow;
                float v = 0.f;
                if ((unsigned)hi < (unsigned)HIN && (unsigned)wi < (unsigned)WIN) {
                    if (IN_NCHW)
                        v = x[(((size_t)n * CIN + c0 + k) * HIN + hi) * WIN + wi];
                    else
                        v = x[(((size_t)n * HIN + hi) * WIN + wi) * CIN + c0 + k];
                }
                Xs[k * XSTR + m] = v;
            }
            __syncthreads();
            // ---- 4x4 register-tile FMA over KC ----
            #pragma unroll
            for (int k = 0; k < KC; ++k) {
                float4 av = *reinterpret_cast<const float4*>(&Xs[k * XSTR + mt * 4]);
                float4 bw = *reinterpret_cast<const float4*>(&Ws[k * N + nt * 4]);
                acc[0][0] += av.x * bw.x; acc[0][1] += av.x * bw.y;
                acc[0][2] += av.x * bw.z; acc[0][3] += av.x * bw.w;
                acc[1][0] += av.y * bw.x; acc[1][1] += av.y * bw.y;
                acc[1][2] += av.y * bw.z; acc[1][3] += av.y * bw.w;
                acc[2][0] += av.z * bw.x; acc[2][1] += av.z * bw.y;
                acc[2][2] += av.z * bw.z; acc[2][3] += av.z * bw.w;
                acc[3][0] += av.w * bw.x; acc[3][1] += av.w * bw.y;
                acc[3][2] += av.w * bw.z; acc[3][3] += av.w * bw.w;
            }
        }
    }

    if (!FUSE) {
        #pragma unroll
        for (int i = 0; i < 4; ++i) {
            const int m  = mt * 4 + i;
            const int ho = (hq0 + m / MW) * OST + pa;
            const int wo = (wq0 + m % MW) * OST + pb;
            float4 o;
            o.x = fmaxf(acc[i][0] + bv[0], 0.f);
            o.y = fmaxf(acc[i][1] + bv[1], 0.f);
            o.z = fmaxf(acc[i][2] + bv[2], 0.f);
            o.w = fmaxf(acc[i][3] + bv[3], 0.f);
            *reinterpret_cast<float4*>(&y[(((size_t)n * HOUT + ho) * WOUT + wo) * N + nt * 4]) = o;
        }
    } else {
        // dec3 (relu) -> LDS -> fused 1x1 conv 16->3 -> NCHW output
        __syncthreads();
        #pragma unroll
        for (int i = 0; i < 4; ++i)
            #pragma unroll
            for (int j = 0; j < 4; ++j)
                Xs[(mt * 4 + i) * 17 + nt * 4 + j] = fmaxf(acc[i][j] + bv[j], 0.f);
        __syncthreads();
        const int m  = tid;                      // M == 256
        const int ho = hq0 + m / MW;
        const int wo = wq0 + m % MW;
        float v[16];
        #pragma unroll
        for (int ci = 0; ci < 16; ++ci) v[ci] = Xs[m * 17 + ci];
        #pragma unroll
        for (int co = 0; co < 3; ++co) {
            float o = b4[co];
            #pragma unroll
            for (int ci = 0; ci < 16; ++ci) o += v[ci] * w4[co * 16 + ci];
            y[(((size_t)n * 3 + co) * HOUT + ho) * WOUT + wo] = o;
        }
    }
}

// ============ weight pre-transforms -> wt[t][ci][co] ============
__global__ void wtr_conv(const float* __restrict__ w, float* __restrict__ wt,
                         int COUT, int CIN)   // w[co][ci][9]
{
    int idx = blockIdx.x * blockDim.x + threadIdx.x;
    if (idx >= COUT * CIN * 9) return;
    int co = idx / (CIN * 9);
    int r  = idx - co * CIN * 9;
    int ci = r / 9, t = r - ci * 9;
    wt[((size_t)t * CIN + ci) * COUT + co] = w[idx];
}
__global__ void wtr_convt(const float* __restrict__ w, float* __restrict__ wt,
                          int CIN, int COUT)  // w[ci][co][9]
{
    int idx = blockIdx.x * blockDim.x + threadIdx.x;
    if (idx >= CIN * COUT * 9) return;
    int ci = idx / (COUT * 9);
    int r  = idx - ci * COUT * 9;
    int co = r / 9, t = r - co * 9;
    wt[((size_t)t * CIN + ci) * COUT + co] = w[idx];
}

// ---------------- embedding: sigmoid(h3_nhwc . kw^T + kb) ----------------
__global__ void emb_kernel(const float* __restrict__ h3, const float* __restrict__ kw,
                           const float* __restrict__ kb, float* __restrict__ emb)
{
    __shared__ float rt[64 * 68];               // [ci][p], padded stride 68
    const int n = blockIdx.x;
    const float4* src = (const float4*)(h3 + (size_t)n * 4096);
    for (int k4 = threadIdx.x; k4 < 1024; k4 += blockDim.x) {
        float4 v = src[k4];
        int k = k4 * 4, p = k >> 6, ci = k & 63;   // NHWC flat: k = p*64 + ci
        rt[(ci + 0) * 68 + p] = v.x;
        rt[(ci + 1) * 68 + p] = v.y;
        rt[(ci + 2) * 68 + p] = v.z;
        rt[(ci + 3) * 68 + p] = v.w;
    }
    __syncthreads();
    const int e = threadIdx.x;
    if (e < 110) {
        const float4* kwr = (const float4*)(kw + (size_t)e * 4096);
        float s0 = 0.f, s1 = 0.f, s2 = 0.f, s3 = 0.f;
        for (int k4 = 0; k4 < 1024; ++k4) {
            float4 wv = kwr[k4];
            int k = k4 * 4, ci = k >> 6, p = k & 63;  // kw flat: k = ci*64 + p
            const float* rp = &rt[ci * 68 + p];
            s0 += rp[0] * wv.x; s1 += rp[1] * wv.y;
            s2 += rp[2] * wv.z; s3 += rp[3] * wv.w;
        }
        float acc = kb[e] + ((s0 + s1) + (s2 + s3));
        emb[(size_t)n * 110 + e] = 1.f / (1.f + expf(-acc));
    }
}

// ---------------- KDE ----------------
__global__ void kde_kernel(const float* __restrict__ emb, float* __restrict__ fd)
{
    int idx = blockIdx.x * blockDim.x + threadIdx.x;
    if (idx >= 64 * 110) return;
    int f = idx % 110, b = idx / 110;
    float dens[11];
    #pragma unroll
    for (int j = 0; j < 11; ++j) dens[j] = 0.f;
    const float* ep = emb + (size_t)b * 32 * 110 + f;
    for (int n = 0; n < 32; ++n) {
        float e = ep[n * 110];
        #pragma unroll
        for (int j = 0; j < 11; ++j) {
            float d = 0.1f * j - e;
            dens[j] += expf(-50.f * d * d);
        }
    }
    float s = 0.f;
    #pragma unroll
    for (int j = 0; j < 11; ++j) s += dens[j];
    float inv = 1.f / s;
    float* op = fd + (size_t)b * 1210 + f * 11;
    #pragma unroll
    for (int j = 0; j < 11; ++j) op[j] = dens[j] * inv;
}

// ---------------- dense ----------------
template<int K, int OUT>
__global__ void dense_kernel(const float* __restrict__ in, const float* __restrict__ w,
                             const float* __restrict__ b, float* __restrict__ out,
                             int rows, int relu)
{
    int idx = blockIdx.x * blockDim.x + threadIdx.x;
    if (idx >= rows * OUT) return;
    int o = idx % OUT, r = idx / OUT;
    float acc = b[o];
    const float* ir = in + (size_t)r * K;
    const float* wr = w  + (size_t)o * K;
    for (int k = 0; k < K; ++k) acc += ir[k] * wr[k];
    if (relu) acc = fmaxf(acc, 0.f);
    out[idx] = acc;
}

// ===================== host side =====================
static Taps4 mk_conv9()   // regular conv / pad 1: oh = kh-1
{
    Taps4 T = {};
    T.t[0].n = 9;
    int q = 0;
    for (int kh = 0; kh < 3; ++kh)
        for (int kw = 0; kw < 3; ++kw) {
            T.t[0].oh[q] = kh - 1; T.t[0].ow[q] = kw - 1; T.t[0].ti[q] = kh * 3 + kw; ++q;
        }
    return T;
}
static Taps4 mk_convt1()  // convT stride 1: hi = ho + 1 - kh
{
    Taps4 T = {};
    T.t[0].n = 9;
    int q = 0;
    for (int kh = 0; kh < 3; ++kh)
        for (int kw = 0; kw < 3; ++kw) {
            T.t[0].oh[q] = 1 - kh; T.t[0].ow[q] = 1 - kw; T.t[0].ti[q] = kh * 3 + kw; ++q;
        }
    return T;
}
static Taps4 mk_convt2()  // convT stride 2, classes (pa,pb): hi = hq + (pa+1-kh)/2 when parity ok
{
    Taps4 T = {};
    for (int cls = 0; cls < 4; ++cls) {
        int pa = cls >> 1, pb = cls & 1, q = 0;
        for (int kh = 0; kh < 3; ++kh) {
            if ((pa + 1 - kh) & 1) continue;
            int oh = (pa + 1 - kh) / 2;
            for (int kw = 0; kw < 3; ++kw) {
                if ((pb + 1 - kw) & 1) continue;
                int ow = (pb + 1 - kw) / 2;
                T.t[cls].oh[q] = oh; T.t[cls].ow[q] = ow; T.t[cls].ti[q] = kh * 3 + kw; ++q;
            }
        }
        T.t[cls].n = q;
    }
    return T;
}

extern "C" void kernel_launch(void* const* d_in, const int* in_sizes, int n_in,
                              void* d_out, int out_size, void* d_ws, size_t ws_size,
                              hipStream_t stream)
{
    const float* x    = (const float*)d_in[0];
    const float* ew1  = (const float*)d_in[1];
    const float* eb1  = (const float*)d_in[2];
    const float* ew2  = (const float*)d_in[3];
    const float* eb2  = (const float*)d_in[4];
    const float* ew3  = (const float*)d_in[5];
    const float* eb3  = (const float*)d_in[6];
    const float* kw   = (const float*)d_in[7];
    const float* kb   = (const float*)d_in[8];
    const float* dw1  = (const float*)d_in[9];
    const float* db1  = (const float*)d_in[10];
    const float* dw2  = (const float*)d_in[11];
    const float* db2  = (const float*)d_in[12];
    const float* dw3  = (const float*)d_in[13];
    const float* db3  = (const float*)d_in[14];
    const float* dw4  = (const float*)d_in[15];
    const float* db4  = (const float*)d_in[16];
    const float* f1w  = (const float*)d_in[17];
    const float* f1b  = (const float*)d_in[18];
    const float* f2w  = (const float*)d_in[19];
    const float* f2b_ = (const float*)d_in[20];
    const float* f3w  = (const float*)d_in[21];
    const float* f3b  = (const float*)d_in[22];

    // ---------- workspace ----------
    char* ws = (char*)d_ws;
    float* emb = (float*)(ws + 0);         //   901,120
    float* fd  = (float*)(ws + 901120);    //   309,760
    float* m1  = (float*)(ws + 1210880);   //   131,072
    float* m2  = (float*)(ws + 1341952);   //    65,536
    float* wt1 = (float*)(ws + 1407488);   //     1,792 (9*3*16)
    float* wt2 = (float*)(ws + 1409280);   //    18,432 (9*16*32)
    float* wt3 = (float*)(ws + 1427712);   //    73,728 (9*32*64)
    float* wt4 = (float*)(ws + 1501440);   //   147,456 (9*64*64)
    float* wt5 = (float*)(ws + 1648896);   //    73,728 (9*64*32)
    float* wt6 = (float*)(ws + 1722624);   //    18,432 (9*32*16)
    const size_t FIXED = 1741056;

    // per image (NHWC fp32): h1 64K | h2 32K | h3 16K | d2 128K  (d1 overlays h1)
    const size_t PER_IMG = 245760;
    int CHUNK = 256;
    while (CHUNK > 8 && FIXED + (size_t)CHUNK * PER_IMG > ws_size) CHUNK >>= 1;
    const int NCHUNK = 2048 / CHUNK;

    char* p   = ws + FIXED;
    float* h1 = (float*)(p);
    float* h2 = (float*)(p + (size_t)CHUNK * 65536);
    float* h3 = (float*)(p + (size_t)CHUNK * 98304);
    float* d2 = (float*)(p + (size_t)CHUNK * 114688);
    float* d1 = h1;

    float* logits = (float*)d_out;               // 64*4
    float* dec    = (float*)d_out + 256;         // 2048*3*32*32 NCHW

    // ---- weight transforms (once) ----
    wtr_conv <<<(16*3*9  + 255)/256, 256, 0, stream>>>(ew1, wt1, 16, 3);
    wtr_conv <<<(32*16*9 + 255)/256, 256, 0, stream>>>(ew2, wt2, 32, 16);
    wtr_conv <<<(64*32*9 + 255)/256, 256, 0, stream>>>(ew3, wt3, 64, 32);
    wtr_convt<<<(64*64*9 + 255)/256, 256, 0, stream>>>(dw1, wt4, 64, 64);
    wtr_convt<<<(64*32*9 + 255)/256, 256, 0, stream>>>(dw2, wt5, 64, 32);
    wtr_convt<<<(32*16*9 + 255)/256, 256, 0, stream>>>(dw3, wt6, 32, 16);

    const Taps4 T9  = mk_conv9();
    const Taps4 TT1 = mk_convt1();
    const Taps4 TT2 = mk_convt2();

    for (int c = 0; c < NCHUNK; ++c) {
        const float* xc   = x   + (size_t)c * CHUNK * 3 * 1024;
        float*       decc = dec + (size_t)c * CHUNK * 3 * 1024;
        float*       embc = emb + (size_t)c * CHUNK * 110;

        // encoder
        conv_gemm<3,16,32,32,32,32, 1,1, 16,16, 3, true, false>
            <<<dim3(CHUNK*4,1), 256, 0, stream>>>(xc, wt1, eb1, h1, T9, nullptr, nullptr);
        conv_gemm<16,32,32,32,16,16, 2,1, 8,16, 16, false, false>
            <<<dim3(CHUNK*2,1), 256, 0, stream>>>(h1, wt2, eb2, h2, T9, nullptr, nullptr);
        conv_gemm<32,64,16,16,8,8, 2,1, 8,8, 16, false, false>
            <<<dim3(CHUNK,1), 256, 0, stream>>>(h2, wt3, eb3, h3, T9, nullptr, nullptr);

        // embedding
        emb_kernel<<<CHUNK, 128, 0, stream>>>(h3, kw, kb, embc);

        // decoder
        conv_gemm<64,64,8,8,16,16, 1,2, 8,8, 16, false, false>
            <<<dim3(CHUNK,4), 256, 0, stream>>>(h3, wt4, db1, d1, TT2, nullptr, nullptr);
        conv_gemm<64,32,16,16,32,32, 1,2, 8,16, 16, false, false>
            <<<dim3(CHUNK*2,4), 256, 0, stream>>>(d1, wt5, db2, d2, TT2, nullptr, nullptr);
        conv_gemm<32,16,32,32,32,32, 1,1, 16,16, 16, false, true>
            <<<dim3(CHUNK*4,1), 256, 0, stream>>>(d2, wt6, db3, decc, TT1, dw4, db4);
    }

    // classifier
    kde_kernel<<<(64*110+255)/256, 256, 0, stream>>>(emb, fd);
    dense_kernel<1210,512><<<(64*512+255)/256, 256, 0, stream>>>(fd, f1w, f1b, m1, 64, 1);
    dense_kernel<512,256><<<(64*256+255)/256, 256, 0, stream>>>(m1, f2w, f2b_, m2, 64, 1);
    dense_kernel<256,4><<<1, 256, 0, stream>>>(m2, f3w, f3b, logits, 64, 0);
}